// Round 3
// baseline (253.424 us; speedup 1.0000x reference)
//
#include <hip/hip_runtime.h>

// RoPE3D encoder: cos/sin tables for (T=32, H=64, W=64), DIM=192.
// Output: [cos (N*192 f32)] ++ [sin (N*192 f32)], N = 131072. 192 MiB total.
//
// Fill-style grid-stride kernel. gridSize = 393216 is divisible by 48, so each
// thread's float4-column c = i%48 is loop-invariant; the per-iter row stride is
// 393216/48 = 8192 rows = 2 full (h,w) planes, so w and h are loop-invariant
// and only t advances (+2 per iter). Threads on the w/h axes (2/3 of lanes)
// compute sin/cos ONCE and then purely stream stores; t-axis lanes recompute
// under predication. All transcendentals are raw HW ops in revolution domain.

#define NPOS (32 * 64 * 64)   // 131072
#define DIM 192
#define TOTAL4 (NPOS * 48)    // 6,291,456 float4-groups
#define NBLK 1536
#define NTHR 256
#define GSIZE (NBLK * NTHR)   // 393,216 ; TOTAL4/GSIZE = 16 exact
#define ITERS (TOTAL4 / GSIZE)

// -log2(10000)/32
#define NEG_C (-0.41524101186092027f)
// log2(1/(2*pi))
#define LOG2_INV_2PI (-2.6514961294723187f)
// 10000^(-1/32), ^(-2/32), ^(-3/32)
#define R1 0.7498942093324559f
#define R2 0.5623413251903491f
#define R3 0.4216965034285822f

__global__ __launch_bounds__(NTHR) void rope3d_kernel(float* __restrict__ out) {
    const unsigned int g = blockIdx.x * NTHR + threadIdx.x;
    const unsigned int r0 = g / 48u;
    const unsigned int c = g - r0 * 48u;          // loop-invariant column
    const unsigned int axis = c >> 4;             // 0:w 1:h 2:t

    // loop-invariant frequencies (revolutions per position step)
    const unsigned int inner0 = (c * 4u) & 31u;
    const float fr0 = __builtin_exp2f(fmaf((float)inner0, NEG_C, LOG2_INV_2PI));
    const float fr1 = fr0 * R1;
    const float fr2 = fr0 * R2;
    const float fr3 = fr0 * R3;

    // initial position component
    const unsigned int w = r0 & 63u;
    const unsigned int h = (r0 >> 6) & 63u;
    const unsigned int t = r0 >> 12;              // in {0,1}
    float pos = (float)(axis == 0 ? w : (axis == 1 ? h : t));

    float a0 = __builtin_amdgcn_fractf(pos * fr0);
    float a1 = __builtin_amdgcn_fractf(pos * fr1);
    float a2 = __builtin_amdgcn_fractf(pos * fr2);
    float a3 = __builtin_amdgcn_fractf(pos * fr3);
    float c0 = __builtin_amdgcn_cosf(a0), s0 = __builtin_amdgcn_sinf(a0);
    float c1 = __builtin_amdgcn_cosf(a1), s1 = __builtin_amdgcn_sinf(a1);
    float c2 = __builtin_amdgcn_cosf(a2), s2 = __builtin_amdgcn_sinf(a2);
    float c3 = __builtin_amdgcn_cosf(a3), s3 = __builtin_amdgcn_sinf(a3);

    float* pc = out + (size_t)g * 4u;
    float* ps = out + (size_t)NPOS * DIM + (size_t)g * 4u;

#pragma unroll 1
    for (int k = 0; k < ITERS; ++k) {
        *(float4*)pc = make_float4(c0, c1, c2, c3);
        *(float4*)ps = make_float4(s0, s1, s2, s3);
        pc += (size_t)GSIZE * 4u;
        ps += (size_t)GSIZE * 4u;
        if (axis == 2) {                          // only t advances (+2/iter)
            pos += 2.0f;
            a0 = __builtin_amdgcn_fractf(pos * fr0);
            a1 = __builtin_amdgcn_fractf(pos * fr1);
            a2 = __builtin_amdgcn_fractf(pos * fr2);
            a3 = __builtin_amdgcn_fractf(pos * fr3);
            c0 = __builtin_amdgcn_cosf(a0); s0 = __builtin_amdgcn_sinf(a0);
            c1 = __builtin_amdgcn_cosf(a1); s1 = __builtin_amdgcn_sinf(a1);
            c2 = __builtin_amdgcn_cosf(a2); s2 = __builtin_amdgcn_sinf(a2);
            c3 = __builtin_amdgcn_cosf(a3); s3 = __builtin_amdgcn_sinf(a3);
        }
    }
}

extern "C" void kernel_launch(void* const* d_in, const int* in_sizes, int n_in,
                              void* d_out, int out_size, void* d_ws, size_t ws_size,
                              hipStream_t stream) {
    (void)d_in; (void)in_sizes; (void)n_in; (void)d_ws; (void)ws_size; (void)out_size;
    float* out = (float*)d_out;
    rope3d_kernel<<<NBLK, NTHR, 0, stream>>>(out);
}